// Round 12
// baseline (180.978 us; speedup 1.0000x reference)
//
#include <hip/hip_runtime.h>
#include <math.h>

// ============================================================================
// DIAGNOSTIC ROUND 2 (resubmit; R11 died to container infra, not the kernel):
// convert_all / qkv_gemm / out_gemm grids duplicated 2x (idempotent; duplicate
// blocks write identical bytes) so each surfaces above the ~42us fill cutoff
// in rocprof top-5 with full counters. attn_kernel stays 1x (characterized in
// R6; rewritten in R8). Bodies are the R8 best (147.1 us), no setprio.
// Next round: revert DUP to 1 and apply the counter-indicted fix.
// ============================================================================
#define DUP 2

#define D 768
#define NQKV 2304
#define NH 8
#define HD 96
#define NW 16
#define OVL 32
#define NLINES 8192
#define NCOMB 8256
#define MPAD 8320  // 65 * 128 zero-padded rows
#define CH 64
#define SCALE_Q 0.1020620726159657f
#define COMB_BLOCKS 6240  // MPAD*192/256
#define CONV_BLOCKS (COMB_BLOCKS + 4 * D * D / 1024)

typedef int i32x8 __attribute__((ext_vector_type(8)));
typedef float f32x4 __attribute__((ext_vector_type(4)));
typedef float f32x2 __attribute__((ext_vector_type(2)));

__device__ __forceinline__ unsigned int pk_fp8x4(float a, float b, float c, float d) {
    int u = __builtin_amdgcn_cvt_pk_fp8_f32(a, b, 0, false);
    u = __builtin_amdgcn_cvt_pk_fp8_f32(c, d, u, true);
    return (unsigned int)u;
}
__device__ __forceinline__ unsigned char f2fp8(float v) {
    return (unsigned char)(__builtin_amdgcn_cvt_pk_fp8_f32(v, v, 0, false) & 0xFF);
}
template <bool HI>
__device__ __forceinline__ f32x2 upk(unsigned int u) {
    return __builtin_amdgcn_cvt_pk_f32_fp8((int)u, HI);
}

__device__ __forceinline__ void stage16(const void* g, void* l) {
    __builtin_amdgcn_global_load_lds(
        (const __attribute__((address_space(1))) unsigned int*)g,
        (__attribute__((address_space(3))) unsigned int*)l, 16, 0, 0);
}

// Swizzled staging for 128B rows (qkv/out GEMMs): stored quad s=(ch>>1)&3
// holds logical quad o=(s-row)&3; fragment reads at phys quad (q+row)&3.
__device__ __forceinline__ void stage_sw(const unsigned char* gbase, unsigned char* lds, int ch) {
    const int row = ch >> 3;
    const int half = ch & 1;
    const int o = (((ch >> 1) & 3) - row) & 3;
    stage16(gbase + (size_t)row * D + o * 32 + half * 16, lds + ch * 16);
}

// Same scheme for 96B rows zero-padded to 128B (attn Q/K): logical quad 3
// sources a guaranteed-zero 32B global region (comb's zero-padded tail).
__device__ __forceinline__ void stage96(const unsigned char* growbase, size_t rstride,
                                        const unsigned char* zrow, unsigned char* lds, int ch) {
    const int row = ch >> 3;
    const int half = ch & 1;
    const int o = (((ch >> 1) & 3) - row) & 3;
    const unsigned char* src = (o < 3) ? growbase + (size_t)row * rstride + o * 32 + half * 16
                                       : zrow + half * 16;
    stage16(src, lds + ch * 16);
}

// Bijective XCD-chunked swizzle (m204).
__device__ __forceinline__ int xcd_swz(int lin, int nwg) {
    const int q = nwg >> 3, r = nwg & 7;
    const int x = lin & 7, i = lin >> 3;
    return (x < r ? x * (q + 1) : r * (q + 1) + (x - r) * q) + i;
}

__device__ __forceinline__ float sel4(f32x4 v, int r) {
    const float ab = (r & 1) ? v.y : v.x;
    const float cd = (r & 1) ? v.w : v.z;
    return (r & 2) ? cd : ab;
}

// ---- fused fp32 -> fp8 converts (comb + weights + bias) + main->out copy ---
__global__ __launch_bounds__(256) void convert_all(const float* __restrict__ main_,
                                                   const float* __restrict__ begin_,
                                                   const float* __restrict__ end_,
                                                   const float* __restrict__ in_w,
                                                   const float* __restrict__ in_b,
                                                   const float* __restrict__ out_w,
                                                   unsigned int* __restrict__ comb_dst,
                                                   unsigned int* __restrict__ w_dst,
                                                   float* __restrict__ bias_s,
                                                   float* __restrict__ out) {
    const int bid = blockIdx.x % CONV_BLOCKS;  // DUP mapping
    if (bid < COMB_BLOCKS) {
        const int i = bid * 256 + threadIdx.x;  // dword index over MPAD*192
        const int row = i / 192, c4 = i % 192;
        float4 v = make_float4(0.f, 0.f, 0.f, 0.f);
        if (row < NCOMB) {
            const float* src = (row < OVL) ? begin_ + (size_t)row * D
                             : (row < OVL + NLINES) ? main_ + (size_t)(row - OVL) * D
                                                    : end_ + (size_t)(row - OVL - NLINES) * D;
            v = *(const float4*)(src + c4 * 4);
            // fused main -> out[:, 0:D] copy (left half of final output)
            if (row >= OVL && row < OVL + NLINES)
                *(float4*)(out + (size_t)(row - OVL) * (2 * D) + c4 * 4) = v;
        }
        comb_dst[(size_t)row * 192 + c4] = pk_fp8x4(v.x, v.y, v.z, v.w);
    } else {
        const int j = (bid - COMB_BLOCKS) * 256 + threadIdx.x;  // dwords over 4*D*D
        const int f0 = j * 4;
        const bool is_out = f0 >= 3 * D * D;
        const float4 v = is_out ? *(const float4*)(out_w + (f0 - 3 * D * D))
                                : *(const float4*)(in_w + f0);
        const float s = 16.0f * ((f0 < D * D) ? SCALE_Q : 1.0f);
        w_dst[j] = pk_fp8x4(v.x * s, v.y * s, v.z * s, v.w * s);
        if (bid == COMB_BLOCKS) {
            for (int b = threadIdx.x; b < NQKV; b += 256)
                bias_s[b] = in_b[b] * (b < D ? SCALE_Q : 1.0f);
        }
    }
}

// ---- merged QKV GEMM (MX-fp8, swizzled LDS, counted-vmcnt dbuf) ------------
__global__ __launch_bounds__(256) void qkv_gemm(const unsigned char* __restrict__ comb,
                                                const unsigned char* __restrict__ w_f8,
                                                const float* __restrict__ bias_s,
                                                unsigned char* __restrict__ Qb,
                                                unsigned char* __restrict__ Kb,
                                                unsigned char* __restrict__ Vb) {
    __shared__ __align__(16) unsigned char As[2][128 * 128];
    __shared__ __align__(16) unsigned char Bs[2][128 * 128];
    const int lin = (blockIdx.y % 65) * 18 + blockIdx.x;  // DUP mapping
    const int s = xcd_swz(lin, 18 * 65);
    const int bx = s % 18;
    const int m0 = (s / 18) * 128;
    const int n0 = bx * 128;
    const int tid = threadIdx.x;
    const int lane = tid & 63;
    const int wave = tid >> 6;
    const int wm = (wave & 1) * 64, wn = (wave >> 1) * 64;
    const int q = lane >> 4, l15 = lane & 15;
    const int swq = (q + l15) & 3;

#pragma unroll
    for (int it = 0; it < 4; it++) {
        const int ch = tid + it * 256;
        stage_sw(comb + (size_t)m0 * D, As[0], ch);
        stage_sw(w_f8 + (size_t)n0 * D, Bs[0], ch);
    }

    f32x4 acc[4][4] = {};
    int cur = 0;
    for (int k0 = 0; k0 < D; k0 += 128) {
        if (k0 + 128 < D) {
#pragma unroll
            for (int it = 0; it < 4; it++) {
                const int ch = tid + it * 256;
                stage_sw(comb + (size_t)m0 * D + k0 + 128, As[cur ^ 1], ch);
                stage_sw(w_f8 + (size_t)n0 * D + k0 + 128, Bs[cur ^ 1], ch);
            }
            asm volatile("s_waitcnt vmcnt(8)" ::: "memory");
        } else {
            asm volatile("s_waitcnt vmcnt(0)" ::: "memory");
        }
        __builtin_amdgcn_sched_barrier(0);
        __builtin_amdgcn_s_barrier();  // B1: buf[cur] ready
        __builtin_amdgcn_sched_barrier(0);

        i32x8 af[4], bfr[4];
#pragma unroll
        for (int i = 0; i < 4; i++)
            af[i] = *(const i32x8*)(As[cur] + (wm + i * 16 + l15) * 128 + swq * 32);
#pragma unroll
        for (int j = 0; j < 4; j++)
            bfr[j] = *(const i32x8*)(Bs[cur] + (wn + j * 16 + l15) * 128 + swq * 32);
#pragma unroll
        for (int i = 0; i < 4; i++)
#pragma unroll
            for (int j = 0; j < 4; j++)
                acc[i][j] = __builtin_amdgcn_mfma_scale_f32_16x16x128_f8f6f4(
                    af[i], bfr[j], acc[i][j], 0, 0, 0, 127, 0, 123);

        asm volatile("s_waitcnt lgkmcnt(0)" ::: "memory");
        __builtin_amdgcn_sched_barrier(0);
        __builtin_amdgcn_s_barrier();  // B2: buf[cur] reusable
        __builtin_amdgcn_sched_barrier(0);
        cur ^= 1;
    }

    unsigned char* Cb = (bx < 6) ? Qb : (bx < 12 ? Kb : Vb);
    const int nloc = (bx % 6) * 128;
#pragma unroll
    for (int i = 0; i < 4; i++)
#pragma unroll
        for (int j = 0; j < 4; j++)
#pragma unroll
            for (int r = 0; r < 4; r++) {
                const int row = m0 + wm + i * 16 + q * 4 + r;
                const int col = wn + j * 16 + l15;
                Cb[(size_t)row * D + nloc + col] = f2fp8(acc[i][j][r] + bias_s[bx * 128 + col]);
            }
}

// ---- out proj (MX-fp8, counted-vmcnt double-buffer, 64x128 tiles) ----------
__global__ __launch_bounds__(256) void out_gemm(const unsigned char* __restrict__ ctx,
                                                const unsigned char* __restrict__ w,
                                                const float* __restrict__ bias,
                                                float* __restrict__ out) {
    __shared__ __align__(16) unsigned char As[2][64 * 128];
    __shared__ __align__(16) unsigned char Bs[2][128 * 128];
    const int lin = (blockIdx.y % 128) * 6 + blockIdx.x;  // DUP mapping
    const int s = xcd_swz(lin, 6 * 128);
    const int m0 = (s / 6) * 64;
    const int n0 = (s % 6) * 128;
    const int tid = threadIdx.x;
    const int lane = tid & 63;
    const int wave = tid >> 6;
    const int wn = wave * 32;
    const int q = lane >> 4, l15 = lane & 15;
    const int swq = (q + l15) & 3;

#pragma unroll
    for (int it = 0; it < 2; it++)
        stage_sw(ctx + (size_t)m0 * D, As[0], tid + it * 256);
#pragma unroll
    for (int it = 0; it < 4; it++)
        stage_sw(w + (size_t)n0 * D, Bs[0], tid + it * 256);

    f32x4 acc[4][2] = {};
    int cur = 0;
    for (int k0 = 0; k0 < D; k0 += 128) {
        if (k0 + 128 < D) {
#pragma unroll
            for (int it = 0; it < 2; it++)
                stage_sw(ctx + (size_t)m0 * D + k0 + 128, As[cur ^ 1], tid + it * 256);
#pragma unroll
            for (int it = 0; it < 4; it++)
                stage_sw(w + (size_t)n0 * D + k0 + 128, Bs[cur ^ 1], tid + it * 256);
            asm volatile("s_waitcnt vmcnt(6)" ::: "memory");
        } else {
            asm volatile("s_waitcnt vmcnt(0)" ::: "memory");
        }
        __builtin_amdgcn_sched_barrier(0);
        __builtin_amdgcn_s_barrier();  // B1
        __builtin_amdgcn_sched_barrier(0);

        i32x8 af[4], bfr[2];
#pragma unroll
        for (int i = 0; i < 4; i++)
            af[i] = *(const i32x8*)(As[cur] + (i * 16 + l15) * 128 + swq * 32);
#pragma unroll
        for (int j = 0; j < 2; j++)
            bfr[j] = *(const i32x8*)(Bs[cur] + (wn + j * 16 + l15) * 128 + swq * 32);
#pragma unroll
        for (int i = 0; i < 4; i++)
#pragma unroll
            for (int j = 0; j < 2; j++)
                acc[i][j] = __builtin_amdgcn_mfma_scale_f32_16x16x128_f8f6f4(
                    af[i], bfr[j], acc[i][j], 0, 0, 0, 127, 0, 123);

        asm volatile("s_waitcnt lgkmcnt(0)" ::: "memory");
        __builtin_amdgcn_sched_barrier(0);
        __builtin_amdgcn_s_barrier();  // B2
        __builtin_amdgcn_sched_barrier(0);
        cur ^= 1;
    }

#pragma unroll
    for (int i = 0; i < 4; i++)
#pragma unroll
        for (int j = 0; j < 2; j++)
#pragma unroll
            for (int r = 0; r < 4; r++) {
                const int row = m0 + i * 16 + q * 4 + r;
                const int col = n0 + wn + j * 16 + l15;
                out[(size_t)row * (2 * D) + D + col] = acc[i][j][r] + bias[col];
            }
}

// ---- attention: QK^T on MFMA, in-register softmax, VALU PV (R8 winner) -----
__global__ __launch_bounds__(256, 4) void attn_kernel(const unsigned char* __restrict__ Q,
                                                      const unsigned char* __restrict__ K,
                                                      const unsigned char* __restrict__ V,
                                                      const unsigned char* __restrict__ zrow,
                                                      unsigned char* __restrict__ ctx) {
    const int lin = blockIdx.y * 128 + blockIdx.x;
    const int s = xcd_swz(lin, 128 * 8);
    const int n0 = (s % 128) * CH;
    const int h = s / 128;
    const int tid = threadIdx.x;

    __shared__ __align__(16) unsigned char pool[40960];
    unsigned char* sK = pool;            // 16 KB
    unsigned char* sV = pool + 16384;    // 16 KB
    unsigned char* sQ = pool + 32768;    // 8 KB (sS overlays after QK)
    float* sS = (float*)(pool + 32768);  // [64][17]

    const int l = tid & 63;
    const int wg = tid >> 6;
    const int q = l >> 4, l15 = l & 15;

    // V staging: reg-staged, 8-slot rotation (PV layout), 768 chunks
#pragma unroll
    for (int it = 0; it < 3; it++) {
        const int idx = tid + it * 256;
        const int row = idx / 6, c = idx % 6;
        const int slot = (c + row) & 7;
        *(uint4*)(sV + row * 128 + slot * 16) =
            *(const uint4*)(V + (size_t)(n0 + row) * D + h * HD + c * 16);
    }
    // K staging: 128 rows x 128B zero-padded = 1024 chunks
#pragma unroll
    for (int it = 0; it < 4; it++)
        stage96(K + (size_t)n0 * D + h * HD, D, zrow, sK, tid + it * 256);
    // Q staging: 64 rows x 128B zero-padded = 512 chunks
#pragma unroll
    for (int it = 0; it < 2; it++)
        stage96(Q + (size_t)n0 * D + h * HD, D, zrow, sQ, tid + it * 256);
    __syncthreads();  // drains vmcnt (gll) + lgkmcnt (ds_writes)

    // A fragment: this wave's 16 queries
    const i32x8 af = *(const i32x8*)(sQ + (wg * 16 + l15) * 128 + ((q + l15) & 3) * 32);
    __syncthreads();  // af in regs for ALL waves before sS overlays sQ

    // QK^T: 8 n-tiles; extract this lane's window scores immediately.
    const int rstar = l15 & 3;
    const int e = (l15 >> 2) - q;
    const int mq = wg * 16 + q * 4 + rstar;
    float sc[8];
    float mx = -1e30f;
#pragma unroll
    for (int j = 0; j < 8; j++) {
        const i32x8 bf = *(const i32x8*)(sK + (j * 16 + l15) * 128 + ((q + l15) & 3) * 32);
        f32x4 z = {};
        const f32x4 a = __builtin_amdgcn_mfma_scale_f32_16x16x128_f8f6f4(
            af, bf, z, 0, 0, 0, 127, 0, 127);
        const int d4 = 4 * (j - wg) + e;
        const bool valid = (d4 >= 0) & (d4 <= 16) & (d4 != 8);
        sc[j] = valid ? sel4(a, rstar) : -1e30f;
        mx = fmaxf(mx, sc[j]);
    }
    mx = fmaxf(mx, __shfl_xor(mx, 4));
    mx = fmaxf(mx, __shfl_xor(mx, 8));
    float sum = 0.f;
    float pr[8];
#pragma unroll
    for (int j = 0; j < 8; j++) {
        pr[j] = __expf(sc[j] - mx);  // invalid (-1e30) -> 0
        sum += pr[j];
    }
    sum += __shfl_xor(sum, 4);
    sum += __shfl_xor(sum, 8);
    const float inv = 1.f / sum;
#pragma unroll
    for (int j = 0; j < 8; j++) {
        const int d4 = 4 * (j - wg) + e;
        if ((d4 >= 0) & (d4 <= 16) & (d4 != 8)) {
            const int win = (d4 < 8) ? d4 : d4 - 1;
            sS[mq * 17 + win] = pr[j] * inv;
        }
    }
    __syncthreads();

    // PV: lane l = query, wave wg = feature slice
    float p[NW];
#pragma unroll
    for (int i = 0; i < NW; i++) p[i] = sS[l * 17 + i];
    float acc[24] = {};
#pragma unroll
    for (int i = 0; i < NW; i++) {
        const int lrow = l + 4 * i + (i >= 8 ? 4 : 0);
        const unsigned char* vrow = sV + lrow * 128;
        const float pw = p[i];
#pragma unroll
        for (int c = 0; c < 3; c++) {
            const int off = wg * 24 + c * 8;
            const uint2 vv =
                *(const uint2*)(vrow + (((off >> 4) + lrow) & 7) * 16 + (off & 15));
            const f32x2 a0 = upk<false>(vv.x), a1 = upk<true>(vv.x);
            const f32x2 a2 = upk<false>(vv.y), a3 = upk<true>(vv.y);
            acc[c * 8 + 0] += pw * a0.x;
            acc[c * 8 + 1] += pw * a0.y;
            acc[c * 8 + 2] += pw * a1.x;
            acc[c * 8 + 3] += pw * a1.y;
            acc[c * 8 + 4] += pw * a2.x;
            acc[c * 8 + 5] += pw * a2.y;
            acc[c * 8 + 6] += pw * a3.x;
            acc[c * 8 + 7] += pw * a3.y;
        }
    }
    unsigned char* op = ctx + (size_t)(n0 + l) * D + h * HD + wg * 24;
#pragma unroll
    for (int c = 0; c < 3; c++) {
        const unsigned int u0 =
            pk_fp8x4(acc[c * 8 + 0], acc[c * 8 + 1], acc[c * 8 + 2], acc[c * 8 + 3]);
        const unsigned int u1 =
            pk_fp8x4(acc[c * 8 + 4], acc[c * 8 + 5], acc[c * 8 + 6], acc[c * 8 + 7]);
        *(uint2*)(op + c * 8) = make_uint2(u0, u1);
    }
}

extern "C" void kernel_launch(void* const* d_in, const int* in_sizes, int n_in,
                              void* d_out, int out_size, void* d_ws, size_t ws_size,
                              hipStream_t stream) {
    const float* main_ = (const float*)d_in[0];
    const float* begin_ = (const float*)d_in[1];
    const float* end_ = (const float*)d_in[2];
    const float* in_w = (const float*)d_in[3];
    const float* in_b = (const float*)d_in[4];
    const float* out_w = (const float*)d_in[5];
    const float* out_b = (const float*)d_in[6];
    float* out = (float*)d_out;

    // workspace (~34 MB), all 16B-aligned
    unsigned char* comb_f8 = (unsigned char*)d_ws;             // MPAD*D
    unsigned char* w_f8 = comb_f8 + (size_t)MPAD * D;          // 4*D*D
    unsigned char* Qb = w_f8 + (size_t)4 * D * D;              // MPAD*D
    unsigned char* Kb = Qb + (size_t)MPAD * D;                 // MPAD*D
    unsigned char* Vb = Kb + (size_t)MPAD * D;                 // MPAD*D
    unsigned char* ctx_f8 = Vb + (size_t)MPAD * D;             // NLINES*D
    float* bias_s = (float*)(ctx_f8 + (size_t)NLINES * D);     // NQKV fp32
    // 32B of guaranteed zeros: comb's zero-padded tail rows (>= NCOMB)
    unsigned char* zrow = comb_f8 + (size_t)NCOMB * D;

    convert_all<<<CONV_BLOCKS * DUP, 256, 0, stream>>>(
        main_, begin_, end_, in_w, in_b, out_w, (unsigned int*)comb_f8,
        (unsigned int*)w_f8, bias_s, out);
    qkv_gemm<<<dim3(18, 65 * DUP), 256, 0, stream>>>(comb_f8, w_f8, bias_s, Qb, Kb, Vb);
    attn_kernel<<<dim3(128, NH), 256, 0, stream>>>(Qb + (size_t)OVL * D, Kb, Vb, zrow,
                                                   ctx_f8);
    out_gemm<<<dim3(6, 128 * DUP), 256, 0, stream>>>(ctx_f8, w_f8 + (size_t)3 * D * D,
                                                     out_b, out);
}

// Round 13
// 146.080 us; speedup vs baseline: 1.2389x; 1.2389x over previous
//
#include <hip/hip_runtime.h>
#include <math.h>

#define D 768
#define NQKV 2304
#define NH 8
#define HD 96
#define NW 16
#define OVL 32
#define NLINES 8192
#define NCOMB 8256
#define MPAD 8320  // 65 * 128 zero-padded rows
#define CH 64
#define SCALE_Q 0.1020620726159657f
#define COMB_BLOCKS 6240  // MPAD*192/256
#define CONV_BLOCKS (COMB_BLOCKS + 4 * D * D / 1024)

typedef int i32x8 __attribute__((ext_vector_type(8)));
typedef float f32x4 __attribute__((ext_vector_type(4)));
typedef float f32x2 __attribute__((ext_vector_type(2)));

__device__ __forceinline__ unsigned int pk_fp8x4(float a, float b, float c, float d) {
    int u = __builtin_amdgcn_cvt_pk_fp8_f32(a, b, 0, false);
    u = __builtin_amdgcn_cvt_pk_fp8_f32(c, d, u, true);
    return (unsigned int)u;
}
__device__ __forceinline__ unsigned char f2fp8(float v) {
    return (unsigned char)(__builtin_amdgcn_cvt_pk_fp8_f32(v, v, 0, false) & 0xFF);
}
template <bool HI>
__device__ __forceinline__ f32x2 upk(unsigned int u) {
    return __builtin_amdgcn_cvt_pk_f32_fp8((int)u, HI);
}

__device__ __forceinline__ void stage16(const void* g, void* l) {
    __builtin_amdgcn_global_load_lds(
        (const __attribute__((address_space(1))) unsigned int*)g,
        (__attribute__((address_space(3))) unsigned int*)l, 16, 0, 0);
}

// 16B-slot rotated staging for 128B rows: logical 16B piece j of row r is
// stored at phys slot (j+r)&7, i.e. chunk ch=(r,p) sources piece j=(p-r)&7.
// A wave's b128 fragment reads (slot (2q+h+r)&7, r varying per lane) then
// cover all 8 slots = all 32 banks -> 8 dwords/bank = LDS floor.
// (Old 32B-quad rotation left half the banks idle per instruction: the
// measured 3.59M SQ_LDS_BANK_CONFLICT in R12's qkv diagnostic.)
__device__ __forceinline__ void stage_sw(const unsigned char* gbase, unsigned char* lds, int ch) {
    const int row = ch >> 3;
    const int j = (ch - row) & 7;  // (p - row) & 7, p = ch & 7
    stage16(gbase + (size_t)row * D + j * 16, lds + ch * 16);
}

// Same scheme for 96B rows zero-padded to 128B (attn Q/K): pieces j=6,7
// source a guaranteed-zero global region (comb's zero-padded tail).
__device__ __forceinline__ void stage96(const unsigned char* growbase, size_t rstride,
                                        const unsigned char* zrow, unsigned char* lds, int ch) {
    const int row = ch >> 3;
    const int j = (ch - row) & 7;
    const unsigned char* src = (j < 6) ? growbase + (size_t)row * rstride + j * 16
                                       : zrow + (j - 6) * 16;
    stage16(src, lds + ch * 16);
}

// Fragment load: logical quad q of a row = pieces 2q,2q+1 at rotated slots.
// s0 = (2q + row) & 7 precomputed per-lane (row&7 == l15&7 for all tiles).
__device__ __forceinline__ i32x8 ld_frag(const unsigned char* rowbase, int s0) {
    i32x8 r;
    *(uint4*)&r = *(const uint4*)(rowbase + s0 * 16);
    *(((uint4*)&r) + 1) = *(const uint4*)(rowbase + ((s0 + 1) & 7) * 16);
    return r;
}

// Bijective XCD-chunked swizzle (m204).
__device__ __forceinline__ int xcd_swz(int lin, int nwg) {
    const int q = nwg >> 3, r = nwg & 7;
    const int x = lin & 7, i = lin >> 3;
    return (x < r ? x * (q + 1) : r * (q + 1) + (x - r) * q) + i;
}

__device__ __forceinline__ float sel4(f32x4 v, int r) {
    const float ab = (r & 1) ? v.y : v.x;
    const float cd = (r & 1) ? v.w : v.z;
    return (r & 2) ? cd : ab;
}

// ---- fused fp32 -> fp8 converts (comb + weights + bias) + main->out copy ---
__global__ __launch_bounds__(256) void convert_all(const float* __restrict__ main_,
                                                   const float* __restrict__ begin_,
                                                   const float* __restrict__ end_,
                                                   const float* __restrict__ in_w,
                                                   const float* __restrict__ in_b,
                                                   const float* __restrict__ out_w,
                                                   unsigned int* __restrict__ comb_dst,
                                                   unsigned int* __restrict__ w_dst,
                                                   float* __restrict__ bias_s,
                                                   float* __restrict__ out) {
    const int bid = blockIdx.x;
    if (bid < COMB_BLOCKS) {
        const int i = bid * 256 + threadIdx.x;  // dword index over MPAD*192
        const int row = i / 192, c4 = i % 192;
        float4 v = make_float4(0.f, 0.f, 0.f, 0.f);
        if (row < NCOMB) {
            const float* src = (row < OVL) ? begin_ + (size_t)row * D
                             : (row < OVL + NLINES) ? main_ + (size_t)(row - OVL) * D
                                                    : end_ + (size_t)(row - OVL - NLINES) * D;
            v = *(const float4*)(src + c4 * 4);
            // fused main -> out[:, 0:D] copy (left half of final output)
            if (row >= OVL && row < OVL + NLINES)
                *(float4*)(out + (size_t)(row - OVL) * (2 * D) + c4 * 4) = v;
        }
        comb_dst[(size_t)row * 192 + c4] = pk_fp8x4(v.x, v.y, v.z, v.w);
    } else {
        const int j = (bid - COMB_BLOCKS) * 256 + threadIdx.x;  // dwords over 4*D*D
        const int f0 = j * 4;
        const bool is_out = f0 >= 3 * D * D;
        const float4 v = is_out ? *(const float4*)(out_w + (f0 - 3 * D * D))
                                : *(const float4*)(in_w + f0);
        const float s = 16.0f * ((f0 < D * D) ? SCALE_Q : 1.0f);
        w_dst[j] = pk_fp8x4(v.x * s, v.y * s, v.z * s, v.w * s);
        if (bid == COMB_BLOCKS) {
            for (int b = threadIdx.x; b < NQKV; b += 256)
                bias_s[b] = in_b[b] * (b < D ? SCALE_Q : 1.0f);
        }
    }
}

// ---- merged QKV GEMM (MX-fp8, 8-slot swizzled LDS, counted-vmcnt dbuf) -----
__global__ __launch_bounds__(256) void qkv_gemm(const unsigned char* __restrict__ comb,
                                                const unsigned char* __restrict__ w_f8,
                                                const float* __restrict__ bias_s,
                                                unsigned char* __restrict__ Qb,
                                                unsigned char* __restrict__ Kb,
                                                unsigned char* __restrict__ Vb) {
    __shared__ __align__(16) unsigned char As[2][128 * 128];
    __shared__ __align__(16) unsigned char Bs[2][128 * 128];
    const int lin = blockIdx.y * 18 + blockIdx.x;
    const int s = xcd_swz(lin, 18 * 65);
    const int bx = s % 18;
    const int m0 = (s / 18) * 128;
    const int n0 = bx * 128;
    const int tid = threadIdx.x;
    const int lane = tid & 63;
    const int wave = tid >> 6;
    const int wm = (wave & 1) * 64, wn = (wave >> 1) * 64;
    const int q = lane >> 4, l15 = lane & 15;
    const int sA = (2 * q + l15) & 7;  // (2q + row) & 7, row ≡ l15 (mod 8)

#pragma unroll
    for (int it = 0; it < 4; it++) {
        const int ch = tid + it * 256;
        stage_sw(comb + (size_t)m0 * D, As[0], ch);
        stage_sw(w_f8 + (size_t)n0 * D, Bs[0], ch);
    }

    f32x4 acc[4][4] = {};
    int cur = 0;
    for (int k0 = 0; k0 < D; k0 += 128) {
        if (k0 + 128 < D) {
#pragma unroll
            for (int it = 0; it < 4; it++) {
                const int ch = tid + it * 256;
                stage_sw(comb + (size_t)m0 * D + k0 + 128, As[cur ^ 1], ch);
                stage_sw(w_f8 + (size_t)n0 * D + k0 + 128, Bs[cur ^ 1], ch);
            }
            asm volatile("s_waitcnt vmcnt(8)" ::: "memory");
        } else {
            asm volatile("s_waitcnt vmcnt(0)" ::: "memory");
        }
        __builtin_amdgcn_sched_barrier(0);
        __builtin_amdgcn_s_barrier();  // B1: buf[cur] ready
        __builtin_amdgcn_sched_barrier(0);

        i32x8 af[4], bfr[4];
#pragma unroll
        for (int i = 0; i < 4; i++)
            af[i] = ld_frag(As[cur] + (wm + i * 16 + l15) * 128, sA);
#pragma unroll
        for (int j = 0; j < 4; j++)
            bfr[j] = ld_frag(Bs[cur] + (wn + j * 16 + l15) * 128, sA);
#pragma unroll
        for (int i = 0; i < 4; i++)
#pragma unroll
            for (int j = 0; j < 4; j++)
                acc[i][j] = __builtin_amdgcn_mfma_scale_f32_16x16x128_f8f6f4(
                    af[i], bfr[j], acc[i][j], 0, 0, 0, 127, 0, 123);

        asm volatile("s_waitcnt lgkmcnt(0)" ::: "memory");
        __builtin_amdgcn_sched_barrier(0);
        __builtin_amdgcn_s_barrier();  // B2: buf[cur] reusable
        __builtin_amdgcn_sched_barrier(0);
        cur ^= 1;
    }

    unsigned char* Cb = (bx < 6) ? Qb : (bx < 12 ? Kb : Vb);
    const int nloc = (bx % 6) * 128;
#pragma unroll
    for (int i = 0; i < 4; i++)
#pragma unroll
        for (int j = 0; j < 4; j++)
#pragma unroll
            for (int r = 0; r < 4; r++) {
                const int row = m0 + wm + i * 16 + q * 4 + r;
                const int col = wn + j * 16 + l15;
                Cb[(size_t)row * D + nloc + col] = f2fp8(acc[i][j][r] + bias_s[bx * 128 + col]);
            }
}

// ---- out proj (MX-fp8, 8-slot swizzle, counted-vmcnt dbuf, 64x128 tiles) ---
__global__ __launch_bounds__(256) void out_gemm(const unsigned char* __restrict__ ctx,
                                                const unsigned char* __restrict__ w,
                                                const float* __restrict__ bias,
                                                float* __restrict__ out) {
    __shared__ __align__(16) unsigned char As[2][64 * 128];
    __shared__ __align__(16) unsigned char Bs[2][128 * 128];
    const int lin = blockIdx.y * 6 + blockIdx.x;
    const int s = xcd_swz(lin, 6 * 128);
    const int m0 = (s / 6) * 64;
    const int n0 = (s % 6) * 128;
    const int tid = threadIdx.x;
    const int lane = tid & 63;
    const int wave = tid >> 6;
    const int wn = wave * 32;
    const int q = lane >> 4, l15 = lane & 15;
    const int sA = (2 * q + l15) & 7;

#pragma unroll
    for (int it = 0; it < 2; it++)
        stage_sw(ctx + (size_t)m0 * D, As[0], tid + it * 256);
#pragma unroll
    for (int it = 0; it < 4; it++)
        stage_sw(w + (size_t)n0 * D, Bs[0], tid + it * 256);

    f32x4 acc[4][2] = {};
    int cur = 0;
    for (int k0 = 0; k0 < D; k0 += 128) {
        if (k0 + 128 < D) {
#pragma unroll
            for (int it = 0; it < 2; it++)
                stage_sw(ctx + (size_t)m0 * D + k0 + 128, As[cur ^ 1], tid + it * 256);
#pragma unroll
            for (int it = 0; it < 4; it++)
                stage_sw(w + (size_t)n0 * D + k0 + 128, Bs[cur ^ 1], tid + it * 256);
            asm volatile("s_waitcnt vmcnt(6)" ::: "memory");
        } else {
            asm volatile("s_waitcnt vmcnt(0)" ::: "memory");
        }
        __builtin_amdgcn_sched_barrier(0);
        __builtin_amdgcn_s_barrier();  // B1
        __builtin_amdgcn_sched_barrier(0);

        i32x8 af[4], bfr[2];
#pragma unroll
        for (int i = 0; i < 4; i++)
            af[i] = ld_frag(As[cur] + (i * 16 + l15) * 128, sA);
#pragma unroll
        for (int j = 0; j < 2; j++)
            bfr[j] = ld_frag(Bs[cur] + (wn + j * 16 + l15) * 128, sA);
#pragma unroll
        for (int i = 0; i < 4; i++)
#pragma unroll
            for (int j = 0; j < 2; j++)
                acc[i][j] = __builtin_amdgcn_mfma_scale_f32_16x16x128_f8f6f4(
                    af[i], bfr[j], acc[i][j], 0, 0, 0, 127, 0, 123);

        asm volatile("s_waitcnt lgkmcnt(0)" ::: "memory");
        __builtin_amdgcn_sched_barrier(0);
        __builtin_amdgcn_s_barrier();  // B2
        __builtin_amdgcn_sched_barrier(0);
        cur ^= 1;
    }

#pragma unroll
    for (int i = 0; i < 4; i++)
#pragma unroll
        for (int j = 0; j < 2; j++)
#pragma unroll
            for (int r = 0; r < 4; r++) {
                const int row = m0 + i * 16 + q * 4 + r;
                const int col = n0 + wn + j * 16 + l15;
                out[(size_t)row * (2 * D) + D + col] = acc[i][j][r] + bias[col];
            }
}

// ---- attention: QK^T on MFMA (8-slot swizzled Q/K), in-reg softmax, VALU PV -
__global__ __launch_bounds__(256, 4) void attn_kernel(const unsigned char* __restrict__ Q,
                                                      const unsigned char* __restrict__ K,
                                                      const unsigned char* __restrict__ V,
                                                      const unsigned char* __restrict__ zrow,
                                                      unsigned char* __restrict__ ctx) {
    const int lin = blockIdx.y * 128 + blockIdx.x;
    const int s = xcd_swz(lin, 128 * 8);
    const int n0 = (s % 128) * CH;
    const int h = s / 128;
    const int tid = threadIdx.x;

    __shared__ __align__(16) unsigned char pool[40960];
    unsigned char* sK = pool;            // 16 KB
    unsigned char* sV = pool + 16384;    // 16 KB
    unsigned char* sQ = pool + 32768;    // 8 KB (sS overlays after QK)
    float* sS = (float*)(pool + 32768);  // [64][17]

    const int l = tid & 63;
    const int wg = tid >> 6;
    const int q = l >> 4, l15 = l & 15;

    // V staging: reg-staged, 8-slot rotation (PV layout), 768 chunks
#pragma unroll
    for (int it = 0; it < 3; it++) {
        const int idx = tid + it * 256;
        const int row = idx / 6, c = idx % 6;
        const int slot = (c + row) & 7;
        *(uint4*)(sV + row * 128 + slot * 16) =
            *(const uint4*)(V + (size_t)(n0 + row) * D + h * HD + c * 16);
    }
    // K staging: 128 rows x 128B zero-padded = 1024 chunks
#pragma unroll
    for (int it = 0; it < 4; it++)
        stage96(K + (size_t)n0 * D + h * HD, D, zrow, sK, tid + it * 256);
    // Q staging: 64 rows x 128B zero-padded = 512 chunks
#pragma unroll
    for (int it = 0; it < 2; it++)
        stage96(Q + (size_t)n0 * D + h * HD, D, zrow, sQ, tid + it * 256);
    __syncthreads();  // drains vmcnt (gll) + lgkmcnt (ds_writes)

    // A fragment: this wave's 16 queries
    const int sA = (2 * q + l15) & 7;
    const i32x8 af = ld_frag(sQ + (wg * 16 + l15) * 128, sA);
    __syncthreads();  // af in regs for ALL waves before sS overlays sQ

    // QK^T: 8 n-tiles; extract this lane's window scores immediately.
    const int rstar = l15 & 3;
    const int e = (l15 >> 2) - q;
    const int mq = wg * 16 + q * 4 + rstar;
    float sc[8];
    float mx = -1e30f;
#pragma unroll
    for (int j = 0; j < 8; j++) {
        const i32x8 bf = ld_frag(sK + (j * 16 + l15) * 128, sA);
        f32x4 z = {};
        const f32x4 a = __builtin_amdgcn_mfma_scale_f32_16x16x128_f8f6f4(
            af, bf, z, 0, 0, 0, 127, 0, 127);
        const int d4 = 4 * (j - wg) + e;
        const bool valid = (d4 >= 0) & (d4 <= 16) & (d4 != 8);
        sc[j] = valid ? sel4(a, rstar) : -1e30f;
        mx = fmaxf(mx, sc[j]);
    }
    mx = fmaxf(mx, __shfl_xor(mx, 4));
    mx = fmaxf(mx, __shfl_xor(mx, 8));
    float sum = 0.f;
    float pr[8];
#pragma unroll
    for (int j = 0; j < 8; j++) {
        pr[j] = __expf(sc[j] - mx);  // invalid (-1e30) -> 0
        sum += pr[j];
    }
    sum += __shfl_xor(sum, 4);
    sum += __shfl_xor(sum, 8);
    const float inv = 1.f / sum;
#pragma unroll
    for (int j = 0; j < 8; j++) {
        const int d4 = 4 * (j - wg) + e;
        if ((d4 >= 0) & (d4 <= 16) & (d4 != 8)) {
            const int win = (d4 < 8) ? d4 : d4 - 1;
            sS[mq * 17 + win] = pr[j] * inv;
        }
    }
    __syncthreads();

    // PV: lane l = query, wave wg = feature slice
    float p[NW];
#pragma unroll
    for (int i = 0; i < NW; i++) p[i] = sS[l * 17 + i];
    float acc[24] = {};
#pragma unroll
    for (int i = 0; i < NW; i++) {
        const int lrow = l + 4 * i + (i >= 8 ? 4 : 0);
        const unsigned char* vrow = sV + lrow * 128;
        const float pw = p[i];
#pragma unroll
        for (int c = 0; c < 3; c++) {
            const int off = wg * 24 + c * 8;
            const uint2 vv =
                *(const uint2*)(vrow + (((off >> 4) + lrow) & 7) * 16 + (off & 15));
            const f32x2 a0 = upk<false>(vv.x), a1 = upk<true>(vv.x);
            const f32x2 a2 = upk<false>(vv.y), a3 = upk<true>(vv.y);
            acc[c * 8 + 0] += pw * a0.x;
            acc[c * 8 + 1] += pw * a0.y;
            acc[c * 8 + 2] += pw * a1.x;
            acc[c * 8 + 3] += pw * a1.y;
            acc[c * 8 + 4] += pw * a2.x;
            acc[c * 8 + 5] += pw * a2.y;
            acc[c * 8 + 6] += pw * a3.x;
            acc[c * 8 + 7] += pw * a3.y;
        }
    }
    unsigned char* op = ctx + (size_t)(n0 + l) * D + h * HD + wg * 24;
#pragma unroll
    for (int c = 0; c < 3; c++) {
        const unsigned int u0 =
            pk_fp8x4(acc[c * 8 + 0], acc[c * 8 + 1], acc[c * 8 + 2], acc[c * 8 + 3]);
        const unsigned int u1 =
            pk_fp8x4(acc[c * 8 + 4], acc[c * 8 + 5], acc[c * 8 + 6], acc[c * 8 + 7]);
        *(uint2*)(op + c * 8) = make_uint2(u0, u1);
    }
}

extern "C" void kernel_launch(void* const* d_in, const int* in_sizes, int n_in,
                              void* d_out, int out_size, void* d_ws, size_t ws_size,
                              hipStream_t stream) {
    const float* main_ = (const float*)d_in[0];
    const float* begin_ = (const float*)d_in[1];
    const float* end_ = (const float*)d_in[2];
    const float* in_w = (const float*)d_in[3];
    const float* in_b = (const float*)d_in[4];
    const float* out_w = (const float*)d_in[5];
    const float* out_b = (const float*)d_in[6];
    float* out = (float*)d_out;

    // workspace (~41 MB), all 16B-aligned
    unsigned char* comb_f8 = (unsigned char*)d_ws;             // MPAD*D
    unsigned char* w_f8 = comb_f8 + (size_t)MPAD * D;          // 4*D*D
    unsigned char* Qb = w_f8 + (size_t)4 * D * D;              // MPAD*D
    unsigned char* Kb = Qb + (size_t)MPAD * D;                 // MPAD*D
    unsigned char* Vb = Kb + (size_t)MPAD * D;                 // MPAD*D
    unsigned char* ctx_f8 = Vb + (size_t)MPAD * D;             // NLINES*D
    float* bias_s = (float*)(ctx_f8 + (size_t)NLINES * D);     // NQKV fp32
    // 32B of guaranteed zeros: comb's zero-padded tail rows (>= NCOMB)
    unsigned char* zrow = comb_f8 + (size_t)NCOMB * D;

    convert_all<<<CONV_BLOCKS, 256, 0, stream>>>(
        main_, begin_, end_, in_w, in_b, out_w, (unsigned int*)comb_f8,
        (unsigned int*)w_f8, bias_s, out);
    qkv_gemm<<<dim3(18, 65), 256, 0, stream>>>(comb_f8, w_f8, bias_s, Qb, Kb, Vb);
    attn_kernel<<<dim3(128, NH), 256, 0, stream>>>(Qb + (size_t)OVL * D, Kb, Vb, zrow,
                                                   ctx_f8);
    out_gemm<<<dim3(6, 128), 256, 0, stream>>>(ctx_f8, w_f8 + (size_t)3 * D * D,
                                               out_b, out);
}